// Round 2
// baseline (141.502 us; speedup 1.0000x reference)
//
#include <hip/hip_runtime.h>
#include <math.h>

// Problem constants
#define D_DOM 64
#define S_RES 512
#define R_ROWS 2048
#define NAA 20
#define NF 12
#define NB 2
#define NJ 24   // NB*NF

// ---------------------------------------------------------------------------
// Kernel A: g[d][k][j][s] = sum_c aa[b,c,d*512+s] * w_conv[f,c,k],  j = b*12+f
// ---------------------------------------------------------------------------
__global__ __launch_bounds__(256) void kA_g(const float* __restrict__ aa,
                                            const float* __restrict__ wconv,
                                            float* __restrict__ g) {
  __shared__ float ws[NF * NAA * 2];
  const int tid = threadIdx.x;
  for (int i = tid; i < NF * NAA * 2; i += 256) ws[i] = wconv[i];  // 480 > 256: strided fill
  __syncthreads();
  const int pos = blockIdx.x * 256 + tid;      // d*512 + s
  float av[NB][NAA];
#pragma unroll
  for (int b = 0; b < NB; ++b)
#pragma unroll
    for (int c = 0; c < NAA; ++c)
      av[b][c] = aa[(size_t)(b * NAA + c) * (D_DOM * S_RES) + pos];
  const int d = pos >> 9;
  const int s = pos & 511;
#pragma unroll
  for (int b = 0; b < NB; ++b)
#pragma unroll
    for (int f = 0; f < NF; ++f) {
      float s0 = 0.f, s1 = 0.f;
#pragma unroll
      for (int c = 0; c < NAA; ++c) {
        const float a = av[b][c];
        s0 = fmaf(a, ws[(f * NAA + c) * 2 + 0], s0);
        s1 = fmaf(a, ws[(f * NAA + c) * 2 + 1], s1);
      }
      const int j = b * NF + f;
      g[((size_t)(d * 2 + 0) * NJ + j) * S_RES + s] = s0;
      g[((size_t)(d * 2 + 1) * NJ + j) * S_RES + s] = s1;
    }
}

// ---------------------------------------------------------------------------
// DPP 64-lane sum (VALU pipe, not DS). Result broadcast via readlane(63).
// old=0 makes invalid-source lanes contribute 0 under either bound_ctrl
// convention.
// ---------------------------------------------------------------------------
__device__ __forceinline__ float wave_sum64(float x) {
  int v;
  v = __builtin_amdgcn_update_dpp(0, __float_as_int(x), 0x111, 0xf, 0xf, true); // row_shr:1
  x += __int_as_float(v);
  v = __builtin_amdgcn_update_dpp(0, __float_as_int(x), 0x112, 0xf, 0xf, true); // row_shr:2
  x += __int_as_float(v);
  v = __builtin_amdgcn_update_dpp(0, __float_as_int(x), 0x114, 0xf, 0xf, true); // row_shr:4
  x += __int_as_float(v);
  v = __builtin_amdgcn_update_dpp(0, __float_as_int(x), 0x118, 0xf, 0xf, true); // row_shr:8
  x += __int_as_float(v);
  v = __builtin_amdgcn_update_dpp(0, __float_as_int(x), 0x142, 0xf, 0xf, true); // row_bcast15
  x += __int_as_float(v);
  v = __builtin_amdgcn_update_dpp(0, __float_as_int(x), 0x143, 0xf, 0xf, true); // row_bcast31
  x += __int_as_float(v);
  return __int_as_float(__builtin_amdgcn_readlane(__float_as_int(x), 63));
}

// ---------------------------------------------------------------------------
// Kernel B: fused single pass over adjs.
// block = (d, pc) : pc in [0,8) covers 128 p (256 rows). 512 blocks x 256 thr.
// wave tj in [0,4) owns j = tj*6+jj ; lane tp owns s in {4tp..4tp+3} U {256+4tp..}
//   h[j,p] = dot(row_even, g0[j]) + dot(row_odd, g1[j])   (64-lane DPP reduce)
//   y[j,s] += h[j,p] * row_even[s]                        (register accum)
//   deg[s] += row_even[s] + row_odd[s]                    (wave 0 only)
// ---------------------------------------------------------------------------
__global__ __launch_bounds__(256) void kB_main(const float* __restrict__ adjs,
                                               const float* __restrict__ g,
                                               float* __restrict__ yp,
                                               float* __restrict__ degp) {
  const int tid = threadIdx.x;
  const int tj = tid >> 6;   // 0..3
  const int tp = tid & 63;
  const int bid = blockIdx.x;
  const int d = bid >> 3;
  const int pc = bid & 7;

  __shared__ float rows[16][S_RES];  // 32 KB stage buffer (16 rows = 8 p-pairs)

  // Preload this thread's g fragments into registers (constant over p-loop).
  float4 g0A[6], g0B[6], g1A[6], g1B[6];
  const float* gd = g + (size_t)d * 2 * NJ * S_RES;
#pragma unroll
  for (int jj = 0; jj < 6; ++jj) {
    const int j = tj * 6 + jj;
    g0A[jj] = *(const float4*)(gd + (size_t)(0 * NJ + j) * S_RES + 4 * tp);
    g0B[jj] = *(const float4*)(gd + (size_t)(0 * NJ + j) * S_RES + 256 + 4 * tp);
    g1A[jj] = *(const float4*)(gd + (size_t)(1 * NJ + j) * S_RES + 4 * tp);
    g1B[jj] = *(const float4*)(gd + (size_t)(1 * NJ + j) * S_RES + 256 + 4 * tp);
  }

  float4 accA[6], accB[6];
#pragma unroll
  for (int jj = 0; jj < 6; ++jj) {
    accA[jj] = make_float4(0.f, 0.f, 0.f, 0.f);
    accB[jj] = make_float4(0.f, 0.f, 0.f, 0.f);
  }
  float4 degA = make_float4(0.f, 0.f, 0.f, 0.f);
  float4 degB = make_float4(0.f, 0.f, 0.f, 0.f);

  const float* ablk = adjs + ((size_t)d * R_ROWS + (size_t)pc * 256) * S_RES;

  for (int batch = 0; batch < 16; ++batch) {
    __syncthreads();
    // stage 16 rows (32 KB global -> LDS), fully coalesced float4
#pragma unroll
    for (int m = 0; m < 8; ++m) {
      const int u = tid + 256 * m;   // 0..2047 float4 units
      const int row = u >> 7;        // 0..15
      const int su = u & 127;
      *(float4*)&rows[row][su * 4] =
          *(const float4*)(ablk + ((size_t)(batch * 16 + row)) * S_RES + su * 4);
    }
    __syncthreads();

#pragma unroll
    for (int pb = 0; pb < 8; ++pb) {
      const float4 reA = *(const float4*)&rows[2 * pb][4 * tp];
      const float4 reB = *(const float4*)&rows[2 * pb][256 + 4 * tp];
      const float4 roA = *(const float4*)&rows[2 * pb + 1][4 * tp];
      const float4 roB = *(const float4*)&rows[2 * pb + 1][256 + 4 * tp];

      if (tj == 0) {  // wave-uniform branch
        degA.x += reA.x + roA.x; degA.y += reA.y + roA.y;
        degA.z += reA.z + roA.z; degA.w += reA.w + roA.w;
        degB.x += reB.x + roB.x; degB.y += reB.y + roB.y;
        degB.z += reB.z + roB.z; degB.w += reB.w + roB.w;
      }

#pragma unroll
      for (int jj = 0; jj < 6; ++jj) {
        float p = reA.x * g0A[jj].x;
        p = fmaf(reA.y, g0A[jj].y, p);
        p = fmaf(reA.z, g0A[jj].z, p);
        p = fmaf(reA.w, g0A[jj].w, p);
        p = fmaf(reB.x, g0B[jj].x, p);
        p = fmaf(reB.y, g0B[jj].y, p);
        p = fmaf(reB.z, g0B[jj].z, p);
        p = fmaf(reB.w, g0B[jj].w, p);
        p = fmaf(roA.x, g1A[jj].x, p);
        p = fmaf(roA.y, g1A[jj].y, p);
        p = fmaf(roA.z, g1A[jj].z, p);
        p = fmaf(roA.w, g1A[jj].w, p);
        p = fmaf(roB.x, g1B[jj].x, p);
        p = fmaf(roB.y, g1B[jj].y, p);
        p = fmaf(roB.z, g1B[jj].z, p);
        p = fmaf(roB.w, g1B[jj].w, p);
        const float h = wave_sum64(p);  // h[j, p] complete, uniform
        accA[jj].x = fmaf(h, reA.x, accA[jj].x);
        accA[jj].y = fmaf(h, reA.y, accA[jj].y);
        accA[jj].z = fmaf(h, reA.z, accA[jj].z);
        accA[jj].w = fmaf(h, reA.w, accA[jj].w);
        accB[jj].x = fmaf(h, reB.x, accB[jj].x);
        accB[jj].y = fmaf(h, reB.y, accB[jj].y);
        accB[jj].z = fmaf(h, reB.z, accB[jj].z);
        accB[jj].w = fmaf(h, reB.w, accB[jj].w);
      }
    }
  }

  // write y partials (per pc) and deg partials
  float* ypb = yp + (size_t)(pc * D_DOM + d) * NJ * S_RES;
#pragma unroll
  for (int jj = 0; jj < 6; ++jj) {
    const int j = tj * 6 + jj;
    *(float4*)(ypb + (size_t)j * S_RES + 4 * tp) = accA[jj];
    *(float4*)(ypb + (size_t)j * S_RES + 256 + 4 * tp) = accB[jj];
  }
  if (tj == 0) {
    float* dp = degp + ((size_t)d * 8 + pc) * S_RES;
    *(float4*)(dp + 4 * tp) = degA;
    *(float4*)(dp + 256 + 4 * tp) = degB;
  }
}

// ---------------------------------------------------------------------------
// Kernel D: reduce yp/degp over pc, max-pool over s, combine, sigmoid.
// One block per domain.
// ---------------------------------------------------------------------------
__global__ __launch_bounds__(256) void kD_final(const float* __restrict__ yp,
                                                const float* __restrict__ degp,
                                                const float* __restrict__ wcomb,
                                                float* __restrict__ out) {
  const int d = blockIdx.x;
  const int tid = threadIdx.x;
  const int tj = tid >> 6;
  __shared__ float wm[NJ][4];
  __shared__ float pool[NJ];

  float dg0 = 0.f, dg1 = 0.f;
#pragma unroll
  for (int pc = 0; pc < 8; ++pc) {
    dg0 += degp[((size_t)d * 8 + pc) * S_RES + tid];
    dg1 += degp[((size_t)d * 8 + pc) * S_RES + 256 + tid];
  }
  const float q0 = 1.0f / dg0;
  const float q1 = 1.0f / dg1;

  for (int j = 0; j < NJ; ++j) {
    float v0 = 0.f, v1 = 0.f;
#pragma unroll
    for (int pc = 0; pc < 8; ++pc) {
      const float* yj = yp + ((size_t)(pc * D_DOM + d) * NJ + j) * S_RES;
      v0 += yj[tid];
      v1 += yj[256 + tid];
    }
    float m = fmaxf(v0 * q0, v1 * q1);
#pragma unroll
    for (int mask = 32; mask; mask >>= 1) m = fmaxf(m, __shfl_xor(m, mask));
    if ((tid & 63) == 0) wm[j][tj] = m;
  }
  __syncthreads();
  if (tid < NJ) {
    float m = wm[tid][0];
    m = fmaxf(m, wm[tid][1]);
    m = fmaxf(m, wm[tid][2]);
    m = fmaxf(m, wm[tid][3]);
    pool[tid] = m;
  }
  __syncthreads();
  if (tid < NB) {
    float sc = 0.f;
#pragma unroll
    for (int f = 0; f < NF; ++f) sc = fmaf(pool[tid * NF + f], wcomb[f], sc);
    out[d * NB + tid] = 1.0f / (1.0f + expf(-sc));
  }
}

// ---------------------------------------------------------------------------
extern "C" void kernel_launch(void* const* d_in, const int* in_sizes, int n_in,
                              void* d_out, int out_size, void* d_ws, size_t ws_size,
                              hipStream_t stream) {
  const float* aa = (const float*)d_in[0];
  const float* adjs = (const float*)d_in[1];
  const float* wconv = (const float*)d_in[2];
  const float* wcomb = (const float*)d_in[3];
  float* out = (float*)d_out;
  float* ws = (float*)d_ws;

  // ws layout (floats): g[64*2*24*512] | yp[8*64*24*512] | degp[64*8*512]
  float* g = ws;                    // 1,572,864 floats
  float* yp = ws + 1572864;         // 6,291,456 floats
  float* degp = ws + 7864320;       //   262,144 floats  (total ~31 MB)

  kA_g<<<dim3(128), dim3(256), 0, stream>>>(aa, wconv, g);
  kB_main<<<dim3(512), dim3(256), 0, stream>>>(adjs, g, yp, degp);
  kD_final<<<dim3(64), dim3(256), 0, stream>>>(yp, degp, wcomb, out);
}